// Round 13
// baseline (148.547 us; speedup 1.0000x reference)
//
#include <hip/hip_runtime.h>
#include <hip/hip_bf16.h>

// Joiner: out[b,t,u,v] = tanh(enc[b,t,:] + pred[b,u,:]) . W[v,:] + bias[v]
// B=8 T=512 U=128 D=256 V=128, fp32 in/out.
// R13 = R12 dataflow (tanh once -> XOR-swizzled LDS joint tile; W+pred+bias
// in registers; lgkmcnt-only s_barrier per t-iter; stores never drained) with:
//  - 256-thread blocks (4 waves), wave = 32u x 32v (W frags 64 VGPR):
//    joint LDS read multiplicity drops 8 -> 4 (chip LDS 2.1 GB -> 1.07 GB).
//  - ~120 VGPR + 32 KB LDS => FOUR independent blocks/CU: their barrier
//    phases interleave, so tanh-VALU / LDS / stores / MFMA overlap instead of
//    summing (R5/R12: 2 domains -> 92 us).
//  - NO __launch_bounds__ min-occupancy arg (R7-R9: 64-VGPR cap + spill).

constexpr int Bn = 8, Tn = 512, Un = 128, Dn = 256, Vn = 128;
constexpr int TCHUNK = 16;
constexpr int UQ = 32;                     // u rows per block (u-quarter)

typedef __attribute__((ext_vector_type(8))) short bf16x8;   // 8 bf16 = 4 VGPRs
typedef __attribute__((ext_vector_type(4))) float f32x4;

static __device__ __forceinline__ unsigned short f2bf(float f) {
    unsigned int u = __float_as_uint(f);
    return (unsigned short)((u + 0x7fffu + ((u >> 16) & 1u)) >> 16);
}
static __device__ __forceinline__ float bf2f(unsigned short h) {
    return __uint_as_float(((unsigned int)h) << 16);
}
// tanh(x) = 1 - 2/(exp(2x)+1); no clamp: e->inf => 1, e->0 => -1 (exact limits)
static __device__ __forceinline__ float fast_tanh(float x) {
    float e = __expf(2.f * x);
    float r = __builtin_amdgcn_rcpf(e + 1.f);
    return __builtin_fmaf(-2.f, r, 1.f);
}

__global__ __launch_bounds__(256) void cvtW_kernel(const float* __restrict__ W,
                                                   unsigned short* __restrict__ Wb) {
    int i = blockIdx.x * 256 + threadIdx.x;          // 32 blocks * 256 * 4 elems = 32768
    float4 v = ((const float4*)W)[i];
    unsigned short r0 = f2bf(v.x), r1 = f2bf(v.y), r2 = f2bf(v.z), r3 = f2bf(v.w);
    unsigned long long packed = (unsigned long long)r0 | ((unsigned long long)r1 << 16) |
                                ((unsigned long long)r2 << 32) | ((unsigned long long)r3 << 48);
    ((unsigned long long*)Wb)[i] = packed;
}

__global__ __launch_bounds__(256) void joiner_kernel(
    const float* __restrict__ enc,         // [B,T,D]
    const float* __restrict__ pred,        // [B,U,D]
    const unsigned short* __restrict__ Wb, // [V,D] bf16 bits
    const float* __restrict__ bias,        // [V]
    float* __restrict__ out)               // [B,T,U,V]
{
    // joint tile: 32 u-rows x 256 d (bf16) as 16B granules, granule ^= (row&7).
    __shared__ unsigned short jointS[2][UQ * 256];   // 2 x 16 KB

    const int bid = blockIdx.x;            // (b*32 + tc)*4 + q
    const int q   = bid & 3;               // u-quarter
    const int tc  = (bid >> 2) & 31;
    const int b   = bid >> 7;
    const int tid = threadIdx.x;
    const int w   = tid >> 6;              // wave 0..3 -> v-cols [w*32, w*32+32)
    const int l16 = tid & 15;
    const int lq  = (tid >> 4) & 3;

    // phase-1 static mapping: thread owns row ur, 32 d at d0 = seg*32
    const int seg = tid & 7;               // 8 segs x 32 d = 256 d
    const int ur  = tid >> 3;              // 0..31

    // ---- persistent state (loaded once per block) ----
    bf16x8 predR[4];                       // 1 row x 32 d, bf16 (16 VGPR)
    {
        const float* pr = pred + ((size_t)(b * Un + q * UQ + ur)) * Dn + seg * 32;
#pragma unroll
        for (int g = 0; g < 4; ++g) {
            float4 a0 = *(const float4*)(pr + g * 8);
            float4 a1 = *(const float4*)(pr + g * 8 + 4);
            bf16x8 qv;
            qv[0] = (short)f2bf(a0.x); qv[1] = (short)f2bf(a0.y);
            qv[2] = (short)f2bf(a0.z); qv[3] = (short)f2bf(a0.w);
            qv[4] = (short)f2bf(a1.x); qv[5] = (short)f2bf(a1.y);
            qv[6] = (short)f2bf(a1.z); qv[7] = (short)f2bf(a1.w);
            predR[g] = qv;
        }
    }

    // W A-frags: wave's 32 v rows (2 n-tiles) x K=256 -> 16 x bf16x8 (64 VGPR)
    bf16x8 wfr[8][2];
#pragma unroll
    for (int kk = 0; kk < 8; ++kk)
#pragma unroll
        for (int n = 0; n < 2; ++n)
            wfr[kk][n] = *(const bf16x8*)(Wb + (size_t)(w * 32 + n * 16 + l16) * Dn
                                          + kk * 32 + lq * 8);

    float4 bv[2];
#pragma unroll
    for (int n = 0; n < 2; ++n)
        bv[n] = *(const float4*)(bias + w * 32 + n * 16 + lq * 4);

    const size_t encBase = (size_t)(b * Tn + tc * TCHUNK) * Dn;

    // tanh(enc + pred) -> swizzled LDS tile (each value computed exactly once)
    auto write_tile = [&](unsigned short* buf, const float ev[32]) {
        const int sw = ur & 7;
#pragma unroll
        for (int g = 0; g < 4; ++g) {
            bf16x8 o;
#pragma unroll
            for (int i = 0; i < 8; ++i)
                o[i] = (short)f2bf(fast_tanh(ev[g * 8 + i] + bf2f((unsigned short)predR[g][i])));
            *(bf16x8*)&buf[((ur * 32) + ((seg * 4 + g) ^ sw)) * 8] = o;
        }
    };
    auto load_enc = [&](int t_idx, float ev[32]) {
        const float* er = enc + encBase + (size_t)t_idx * Dn + seg * 32;
#pragma unroll
        for (int g = 0; g < 8; ++g) {
            float4 a = *(const float4*)(er + g * 4);
            ev[g * 4 + 0] = a.x; ev[g * 4 + 1] = a.y;
            ev[g * 4 + 2] = a.z; ev[g * 4 + 3] = a.w;
        }
    };

    // ---- prologue: tile 0 into buf 0 ----
    {
        float ev[32];
        load_enc(0, ev);
        write_tile(jointS[0], ev);
    }
    asm volatile("s_waitcnt lgkmcnt(0)" ::: "memory");
    __builtin_amdgcn_s_barrier();
    __builtin_amdgcn_sched_barrier(0);

    for (int ti = 0; ti < TCHUNK; ++ti) {
        const unsigned short* cur = jointS[ti & 1];

        // ---------- MFMA: A = W regs (32 v), B = joint tile (32 u) ----------
        f32x4 acc[2][2];                   // [ut][n]
#pragma unroll
        for (int ut = 0; ut < 2; ++ut)
#pragma unroll
            for (int n = 0; n < 2; ++n) acc[ut][n] = (f32x4){0.f, 0.f, 0.f, 0.f};

#pragma unroll
        for (int kk = 0; kk < 8; ++kk) {
            bf16x8 bfr[2];
#pragma unroll
            for (int ut = 0; ut < 2; ++ut) {
                const int row = ut * 16 + l16;
                bfr[ut] = *(const bf16x8*)&cur[((row * 32) + ((kk * 4 + lq) ^ (row & 7))) * 8];
            }
#pragma unroll
            for (int ut = 0; ut < 2; ++ut)
#pragma unroll
                for (int n = 0; n < 2; ++n)
                    acc[ut][n] = __builtin_amdgcn_mfma_f32_16x16x32_bf16(
                        wfr[kk][n], bfr[ut], acc[ut][n], 0, 0, 0);
        }

        // ---------- epilogue: bias + float4 stores (never drained in-loop) ----
        // D row = v-in-tile = lq*4+r, col = u-in-tile = ut*16 + l16
        const size_t rowBase = (size_t)((b * Tn + tc * TCHUNK + ti) * Un + q * UQ);
#pragma unroll
        for (int ut = 0; ut < 2; ++ut) {
            float* ob = out + (rowBase + ut * 16 + l16) * Vn + w * 32 + lq * 4;
#pragma unroll
            for (int n = 0; n < 2; ++n) {
                f32x4 rv;
                rv[0] = acc[ut][n][0] + bv[n].x;
                rv[1] = acc[ut][n][1] + bv[n].y;
                rv[2] = acc[ut][n][2] + bv[n].z;
                rv[3] = acc[ut][n][3] + bv[n].w;
                *(f32x4*)(ob + n * 16) = rv;
            }
        }

        // ---------- next tanh tile into the other buffer ----------
        if (ti + 1 < TCHUNK) {
            float ev[32];
            load_enc(ti + 1, ev);
            write_tile(jointS[(ti + 1) & 1], ev);
            // barrier protects LDS only: wait ds ops, NOT the global stores
            asm volatile("s_waitcnt lgkmcnt(0)" ::: "memory");
            __builtin_amdgcn_s_barrier();
            __builtin_amdgcn_sched_barrier(0);
        }
    }
}

extern "C" void kernel_launch(void* const* d_in, const int* in_sizes, int n_in,
                              void* d_out, int out_size, void* d_ws, size_t ws_size,
                              hipStream_t stream) {
    const float* enc  = (const float*)d_in[0];
    const float* pred = (const float*)d_in[1];
    const float* W    = (const float*)d_in[2];
    const float* bias = (const float*)d_in[3];
    float* out = (float*)d_out;
    unsigned short* Wb = (unsigned short*)d_ws;   // 32768 bf16 = 64 KB

    cvtW_kernel<<<32, 256, 0, stream>>>(W, Wb);
    // grid = B * (T/TCHUNK) * 4 u-quarters = 8 * 32 * 4 = 1024 blocks (256 thr)
    joiner_kernel<<<1024, 256, 0, stream>>>(enc, pred, Wb, bias, out);
}